// Round 5
// baseline (79.976 us; speedup 1.0000x reference)
//
#include <hip/hip_runtime.h>
#include <hip/hip_bf16.h>
#include <hip/hip_fp16.h>

// out[e] = dot(h[src[e]], h[dst[e]]), E=640k, D=128 fp32.
// h is converted once per launch to f16 in d_ws (2.56 MB -> fits each XCD's
// 4 MiB L2; fp32 thrashed it: 97 MB L3 fetch in round 1). Edge kernel:
// 8 lanes/edge, 2 edges per group, gathers as uint4, dot via
// v_dot2_f32_f16 (__builtin_amdgcn_fdot2): 2 f16 mul + fp32 acc per instr,
// ~3x fewer VALU ops than the bf16 shift/mask unpack of round 3/4.

#define D 128

typedef _Float16 half2_t __attribute__((ext_vector_type(2)));

__global__ __launch_bounds__(256) void convert_f16_kernel(
    const float* __restrict__ h, unsigned short* __restrict__ hf, int n4)
{
    int i = blockIdx.x * blockDim.x + threadIdx.x;
    if (i >= n4) return;
    float4 v = reinterpret_cast<const float4*>(h)[i];
    __half2 lo = __floats2half2_rn(v.x, v.y);
    __half2 hi = __floats2half2_rn(v.z, v.w);
    uint2 o;
    o.x = *reinterpret_cast<unsigned int*>(&lo);
    o.y = *reinterpret_cast<unsigned int*>(&hi);
    reinterpret_cast<uint2*>(hf)[i] = o;
}

// dot of 8 f16 pairs held in two uint4 (each uint = half2), fp32 accumulate
__device__ __forceinline__ float dot8_f16(uint4 a, uint4 b, float acc) {
    union U { uint4 u; half2_t h[4]; };
    U ua, ub;
    ua.u = a;
    ub.u = b;
#if __has_builtin(__builtin_amdgcn_fdot2)
    #pragma unroll
    for (int i = 0; i < 4; ++i)
        acc = __builtin_amdgcn_fdot2(ua.h[i], ub.h[i], acc, false);
#else
    #pragma unroll
    for (int i = 0; i < 4; ++i) {
        acc += (float)ua.h[i].x * (float)ub.h[i].x;
        acc += (float)ua.h[i].y * (float)ub.h[i].y;
    }
#endif
    return acc;
}

__global__ __launch_bounds__(256) void edge_dot_f16x2_kernel(
    const unsigned short* __restrict__ hf,
    const int* __restrict__ src,
    const int* __restrict__ dst,
    float* __restrict__ out,
    int E)   // E assumed even (640000)
{
    int tid   = blockIdx.x * blockDim.x + threadIdx.x;
    int group = tid >> 3;        // 8 lanes per group, 2 edges per group
    int lane  = tid & 7;
    int e0 = group * 2;
    if (e0 >= E) return;
    int e1 = e0 + 1;

    int s0 = src[e0];
    int d0 = dst[e0];
    int s1 = src[e1];
    int d1 = dst[e1];

    // row = 128 f16 = 256 B = 16 uint4; lane covers uint4 {lane, lane+8}
    const uint4* pu0 = reinterpret_cast<const uint4*>(hf + (size_t)s0 * D);
    const uint4* pv0 = reinterpret_cast<const uint4*>(hf + (size_t)d0 * D);
    const uint4* pu1 = reinterpret_cast<const uint4*>(hf + (size_t)s1 * D);
    const uint4* pv1 = reinterpret_cast<const uint4*>(hf + (size_t)d1 * D);

    // 8 independent gather loads in flight per lane
    uint4 a00 = pu0[lane];
    uint4 a01 = pu0[lane + 8];
    uint4 b00 = pv0[lane];
    uint4 b01 = pv0[lane + 8];
    uint4 a10 = pu1[lane];
    uint4 a11 = pu1[lane + 8];
    uint4 b10 = pv1[lane];
    uint4 b11 = pv1[lane + 8];

    float sum0 = dot8_f16(a01, b01, dot8_f16(a00, b00, 0.0f));
    float sum1 = dot8_f16(a11, b11, dot8_f16(a10, b10, 0.0f));

    sum0 += __shfl_xor(sum0, 4);
    sum1 += __shfl_xor(sum1, 4);
    sum0 += __shfl_xor(sum0, 2);
    sum1 += __shfl_xor(sum1, 2);
    sum0 += __shfl_xor(sum0, 1);
    sum1 += __shfl_xor(sum1, 1);

    if (lane == 0) {
        reinterpret_cast<float2*>(out)[group] = make_float2(sum0, sum1);
    }
}

// Fallback (fp32 direct gather) if ws is too small for the f16 table.
__global__ __launch_bounds__(256) void edge_dot_f32_kernel(
    const float* __restrict__ h,
    const int* __restrict__ src,
    const int* __restrict__ dst,
    float* __restrict__ out,
    int E)
{
    int tid  = blockIdx.x * blockDim.x + threadIdx.x;
    int edge = tid >> 3;
    int lane = tid & 7;
    if (edge >= E) return;

    int s = src[edge];
    int d = dst[edge];

    const float4* hu = reinterpret_cast<const float4*>(h + (size_t)s * D) + lane;
    const float4* hv = reinterpret_cast<const float4*>(h + (size_t)d * D) + lane;

    float4 a0 = hu[0], a1 = hu[8], a2 = hu[16], a3 = hu[24];
    float4 b0 = hv[0], b1 = hv[8], b2 = hv[16], b3 = hv[24];

    float sum = a0.x * b0.x + a0.y * b0.y + a0.z * b0.z + a0.w * b0.w;
    sum += a1.x * b1.x + a1.y * b1.y + a1.z * b1.z + a1.w * b1.w;
    sum += a2.x * b2.x + a2.y * b2.y + a2.z * b2.z + a2.w * b2.w;
    sum += a3.x * b3.x + a3.y * b3.y + a3.z * b3.z + a3.w * b3.w;

    sum += __shfl_xor(sum, 4);
    sum += __shfl_xor(sum, 2);
    sum += __shfl_xor(sum, 1);

    if (lane == 0)
        out[edge] = sum;
}

extern "C" void kernel_launch(void* const* d_in, const int* in_sizes, int n_in,
                              void* d_out, int out_size, void* d_ws, size_t ws_size,
                              hipStream_t stream)
{
    const float* h   = (const float*)d_in[0];
    const int*   src = (const int*)d_in[1];
    const int*   dst = (const int*)d_in[2];
    float*       out = (float*)d_out;

    int E = in_sizes[1];            // 640000 edges
    int hN = in_sizes[0];           // N_NODES * 128 floats
    size_t need = (size_t)hN * sizeof(unsigned short);

    int threads = 256;

    if (ws_size >= need && (E & 1) == 0) {
        unsigned short* hf = (unsigned short*)d_ws;
        int n4 = hN / 4;
        convert_f16_kernel<<<(n4 + threads - 1) / threads, threads, 0, stream>>>(h, hf, n4);
        long long total = (long long)(E / 2) * 8;   // 8 lanes per 2 edges
        int blocks = (int)((total + threads - 1) / threads);
        edge_dot_f16x2_kernel<<<blocks, threads, 0, stream>>>(hf, src, dst, out, E);
    } else {
        long long total = (long long)E * 8;
        int blocks = (int)((total + threads - 1) / threads);
        edge_dot_f32_kernel<<<blocks, threads, 0, stream>>>(h, src, dst, out, E);
    }
}